// Round 7
// baseline (2523.237 us; speedup 1.0000x reference)
//
#include <hip/hip_runtime.h>
#include <math.h>
#include <stdint.h>

#define T_DATA 20000
#define E_NO   2000
#define I_NO   500
#define SUB    16
#define TNO    200
#define NBLK   313   // ceil(20000/64)

// ---------------- workspace layout (float offsets) ----------------
// 0       ek[3200]   (s*200+t)
// 3200    ik[3200]
// 6400    hist[200]
// 6600    ewsub[16]
// 6616    we[2000]
// 8616    wi[500]
// 16384   synE[20000*16]
// 336384  synI[20000*16]
// 656384  negd[20000]
// 676384  me[2000] (int)
// 678384  mi[500]  (int)
// 678884  cmask[16](int)

// ---------------------------------------------------------------------------
// K1: per-subunit kernels, hist kernel, synapse->subunit maps, tree masks.
// ---------------------------------------------------------------------------
__global__ __launch_bounds__(256) void k_prep(
    const float* __restrict__ Ce, const float* __restrict__ Ci,
    const float* __restrict__ cosb,
    const float* __restrict__ TauE, const float* __restrict__ TauI,
    const float* __restrict__ We,  const float* __restrict__ Wi,
    const float* __restrict__ De,  const float* __restrict__ Di,
    const float* __restrict__ Wsub, const float* __restrict__ Whist,
    const int* __restrict__ Cden,
    float* __restrict__ ws_ek, float* __restrict__ ws_ik,
    float* __restrict__ ws_hist, float* __restrict__ ws_ewsub,
    float* __restrict__ ws_we, float* __restrict__ ws_wi,
    int* __restrict__ ws_me, int* __restrict__ ws_mi, int* __restrict__ ws_cmask,
    float* __restrict__ out_filt) {
  int tid = threadIdx.x;
  for (int idx = tid; idx < SUB * TNO; idx += 256) {
    int s = idx / TNO;
    float tf = (float)(idx % TNO);
    float te  = fmaxf(tf - expf(De[s]), 0.f);
    float tte = te / expf(TauE[s]);
    float ekv = tte * expf(-tte) * expf(We[s]);
    float ti_ = fmaxf(tf - expf(Di[s]), 0.f);
    float tti = ti_ / expf(TauI[s]);
    float ikv = -(tti * expf(-tti) * expf(Wi[s]));
    ws_ek[idx] = ekv;
    ws_ik[idx] = ikv;
    out_filt[idx] = ekv;            // rows 0..15
    out_filt[3200 + idx] = ikv;     // rows 16..31
  }
  for (int t = tid; t < TNO; t += 256) {
    float h = 0.f;
    for (int b = 0; b < 16; ++b) h = fmaf(Whist[b], cosb[b * TNO + t], h);
    ws_hist[t] = h;
    out_filt[6400 + t] = h;         // row 32 (unflipped)
  }
  for (int e = tid; e < E_NO; e += 256) {
    int m = 0; float w = 0.f;
    for (int s = 0; s < SUB; ++s) {
      float v = Ce[s * E_NO + e];
      if (w == 0.f && v != 0.f) { m = s; w = v; }
    }
    ws_me[e] = m; ws_we[e] = w;
  }
  for (int e = tid; e < I_NO; e += 256) {
    int m = 0; float w = 0.f;
    for (int s = 0; s < SUB; ++s) {
      float v = Ci[s * I_NO + e];
      if (w == 0.f && v != 0.f) { m = s; w = v; }
    }
    ws_mi[e] = m; ws_wi[e] = w;
  }
  if (tid < SUB) {
    ws_ewsub[tid] = expf(Wsub[tid]);
    int msk = 0;
    for (int j = 0; j < SUB; ++j)
      if (Cden[tid * SUB + j] == 1) msk |= (1 << j);
    ws_cmask[tid] = msk;
  }
}

// ---------------------------------------------------------------------------
// K2: synapse aggregation -> synE/synI [20000][16]. Deterministic.
// ---------------------------------------------------------------------------
__global__ __launch_bounds__(256) void k_agg(
    const float4* __restrict__ Se4, const float4* __restrict__ Si4,
    const int* __restrict__ me, const float* __restrict__ we,
    const int* __restrict__ mi, const float* __restrict__ wi,
    float* __restrict__ synE, float* __restrict__ synI) {
  __shared__ float bins[4][64][33];
  int tid = threadIdx.x, wid = tid >> 6, l = tid & 63;
  int gw = blockIdx.x * 4 + wid;
  for (int r = 0; r < 4; ++r) {
    int t = gw * 4 + r;
#pragma unroll
    for (int s = 0; s < 32; ++s) bins[wid][l][s] = 0.f;
    for (int i = 0; i < 8; ++i) {
      int idx = i * 64 + l;
      if (idx < 500) {
        float4 v = Se4[(size_t)t * 500 + idx];
        int e0 = idx * 4;
        if (v.x != 0.f) bins[wid][l][me[e0 + 0]] += v.x * we[e0 + 0];
        if (v.y != 0.f) bins[wid][l][me[e0 + 1]] += v.y * we[e0 + 1];
        if (v.z != 0.f) bins[wid][l][me[e0 + 2]] += v.z * we[e0 + 2];
        if (v.w != 0.f) bins[wid][l][me[e0 + 3]] += v.w * we[e0 + 3];
      }
    }
    for (int i = 0; i < 2; ++i) {
      int idx = i * 64 + l;
      if (idx < 125) {
        float4 v = Si4[(size_t)t * 125 + idx];
        int e0 = idx * 4;
        if (v.x != 0.f) bins[wid][l][16 + mi[e0 + 0]] += v.x * wi[e0 + 0];
        if (v.y != 0.f) bins[wid][l][16 + mi[e0 + 1]] += v.y * wi[e0 + 1];
        if (v.z != 0.f) bins[wid][l][16 + mi[e0 + 2]] += v.z * wi[e0 + 2];
        if (v.w != 0.f) bins[wid][l][16 + mi[e0 + 3]] += v.w * wi[e0 + 3];
      }
    }
    __syncthreads();
    if (l < 32) {
      float a = 0.f;
      for (int k = 0; k < 64; ++k) a += bins[wid][k][l];
      if (l < 16) synE[(size_t)t * 16 + l] = a;
      else        synI[(size_t)t * 16 + (l - 16)] = a;
    }
    __syncthreads();
  }
}

// ---------------------------------------------------------------------------
// K3: causal filtering + dendritic tree -> negd[t] = -drive[t].
// ---------------------------------------------------------------------------
__global__ __launch_bounds__(64) void k_filt(
    const float* __restrict__ synE, const float* __restrict__ synI,
    const float* __restrict__ ek_ws, const float* __restrict__ ik_ws,
    const float* __restrict__ theta, const float* __restrict__ ewsub,
    const int* __restrict__ cmask,
    float* __restrict__ negd) {
  __shared__ float sE[264 * 17];
  __shared__ float sI[264 * 17];
  __shared__ float ekl[TNO * 16];
  __shared__ float ikl[TNO * 16];
  int l = threadIdx.x;
  int t0 = blockIdx.x * 64;
  for (int idx = l; idx < 264 * 16; idx += 64) {
    int row = idx >> 4, s = idx & 15;
    int g = t0 - 200 + row;
    bool ok = (g >= 0) && (g < T_DATA);
    sE[row * 17 + s] = ok ? synE[(size_t)g * 16 + s] : 0.f;
    sI[row * 17 + s] = ok ? synI[(size_t)g * 16 + s] : 0.f;
  }
  for (int idx = l; idx < SUB * TNO; idx += 64) {
    int s = idx / TNO, j = idx % TNO;
    ekl[j * 16 + s] = ek_ws[idx];
    ikl[j * 16 + s] = ik_ws[idx];
  }
  __syncthreads();
  int t = t0 + l;
  float acc[16];
#pragma unroll
  for (int s = 0; s < 16; ++s) acc[s] = 0.f;
  for (int j = 0; j < TNO; ++j) {
    int base = (l + 199 - j) * 17;
    int kb = j * 16;
#pragma unroll
    for (int s = 0; s < 16; ++s)
      acc[s] = fmaf(ekl[kb + s], sE[base + s], fmaf(ikl[kb + s], sI[base + s], acc[s]));
  }
  float th[16], ew[16]; int cm[16];
#pragma unroll
  for (int s = 0; s < 16; ++s) { th[s] = theta[s]; ew[s] = ewsub[s]; cm[s] = cmask[s]; }
  float val[16];
#pragma unroll
  for (int s = 0; s < 16; ++s) val[s] = 0.f;
#pragma unroll
  for (int sidx = 15; sidx >= 1; --sidx) {
    float sum = acc[sidx] + th[sidx];
#pragma unroll
    for (int j = 0; j < 16; ++j)
      if ((cm[sidx] >> j) & 1) sum += val[j] * ew[j];
    val[sidx] = tanhf(sum);
  }
  float drive = acc[0] + th[0];
#pragma unroll
  for (int j = 0; j < 16; ++j)
    if ((cm[0] >> j) & 1) drive += val[j] * ew[j];
  if (t < T_DATA) negd[t] = -drive;
}

// ---------------------------------------------------------------------------
// K4: sequential spike scan. 1 workgroup, 4 waves (one per SIMD).
// ROUND 7: rounds 2-6 localized the critical path to wave0's 64-step ballot
// chain (~85 cyc/step regardless of operand residency). Replace it with a
// SPIKE-SPARSE left-to-right finalization loop: feedback flows only forward
// (lane l receives from spikes i<l), so the first ballot bit past the
// resolved prefix is definite; apply its hist[l-q-1] via one __shfl (lane j
// holds hist[j]); re-ballot. Rounds = spikes+1 instead of 64 fixed steps.
// Bits <= pos are stable, so the exit ballot IS the final mask.
// Boundary conv back in registers hb0..hb63 (R6's LDS version was the
// regression). Deep waves keep R6's mask+register form.
// ---------------------------------------------------------------------------
__global__
__attribute__((amdgpu_flat_work_group_size(256, 256), amdgpu_waves_per_eu(1, 1)))
void k_scan(
    const float* __restrict__ hist, const float* __restrict__ negd,
    float* __restrict__ out_spk) {
  __shared__ float hpad[328];        // [0..63]=0, [64..263]=h[0..199], [264..327]=0
  __shared__ unsigned long long mring[8];  // per-block spike masks, slot n&7
  __shared__ float deepb[2][3][64];  // parity double-buffered deep partials
  int tid = threadIdx.x, wid = tid >> 6, l = tid & 63;
  for (int i = tid; i < 328; i += 256) hpad[i] = (i >= 64 && i < 264) ? hist[i - 64] : 0.f;
  if (tid < 8) mring[tid] = 0ull;
  for (int i = tid; i < 2 * 3 * 64; i += 256) (&deepb[0][0][0])[i] = 0.f;
  __syncthreads();

  // wave0: H = hist[l] (shfl source); hb(j) = hpad[l+64+j] (boundary taps:
  // prev-block spike at step i adds hpad[127+l-i] = hb(63-i)).
  float H = 0.f;
  float hb0=0,hb1=0,hb2=0,hb3=0,hb4=0,hb5=0,hb6=0,hb7=0,hb8=0,hb9=0,hb10=0,hb11=0,hb12=0,hb13=0,hb14=0,hb15=0,
        hb16=0,hb17=0,hb18=0,hb19=0,hb20=0,hb21=0,hb22=0,hb23=0,hb24=0,hb25=0,hb26=0,hb27=0,hb28=0,hb29=0,hb30=0,hb31=0,
        hb32=0,hb33=0,hb34=0,hb35=0,hb36=0,hb37=0,hb38=0,hb39=0,hb40=0,hb41=0,hb42=0,hb43=0,hb44=0,hb45=0,hb46=0,hb47=0,
        hb48=0,hb49=0,hb50=0,hb51=0,hb52=0,hb53=0,hb54=0,hb55=0,hb56=0,hb57=0,hb58=0,hb59=0,hb60=0,hb61=0,hb62=0,hb63=0;
  // deep-wave tap registers: hd(j) = hpad[dbase + l + j]
  float hd0=0,hd1=0,hd2=0,hd3=0,hd4=0,hd5=0,hd6=0,hd7=0,hd8=0,hd9=0,hd10=0,hd11=0,hd12=0,hd13=0,hd14=0,hd15=0,
        hd16=0,hd17=0,hd18=0,hd19=0,hd20=0,hd21=0,hd22=0,hd23=0,hd24=0,hd25=0,hd26=0,hd27=0,hd28=0,hd29=0,hd30=0,hd31=0,
        hd32=0,hd33=0,hd34=0,hd35=0,hd36=0,hd37=0,hd38=0,hd39=0,hd40=0,hd41=0,hd42=0,hd43=0,hd44=0,hd45=0;
  if (wid == 0) {
    H = hpad[64 + l];
#define LHB(j) hb##j = hpad[l + 64 + j];
    LHB(0)LHB(1)LHB(2)LHB(3)LHB(4)LHB(5)LHB(6)LHB(7)LHB(8)LHB(9)LHB(10)LHB(11)LHB(12)LHB(13)LHB(14)LHB(15)
    LHB(16)LHB(17)LHB(18)LHB(19)LHB(20)LHB(21)LHB(22)LHB(23)LHB(24)LHB(25)LHB(26)LHB(27)LHB(28)LHB(29)LHB(30)LHB(31)
    LHB(32)LHB(33)LHB(34)LHB(35)LHB(36)LHB(37)LHB(38)LHB(39)LHB(40)LHB(41)LHB(42)LHB(43)LHB(44)LHB(45)LHB(46)LHB(47)
    LHB(48)LHB(49)LHB(50)LHB(51)LHB(52)LHB(53)LHB(54)LHB(55)LHB(56)LHB(57)LHB(58)LHB(59)LHB(60)LHB(61)LHB(62)LHB(63)
#undef LHB
  } else {
    int dbase = (wid == 2) ? 174 : (wid == 3) ? 219 : 128;
#define LHD(j) hd##j = hpad[dbase + l + j];
    LHD(0)LHD(1)LHD(2)LHD(3)LHD(4)LHD(5)LHD(6)LHD(7)LHD(8)LHD(9)LHD(10)LHD(11)LHD(12)LHD(13)LHD(14)LHD(15)
    LHD(16)LHD(17)LHD(18)LHD(19)LHD(20)LHD(21)LHD(22)LHD(23)LHD(24)LHD(25)LHD(26)LHD(27)LHD(28)LHD(29)LHD(30)LHD(31)
    LHD(32)LHD(33)LHD(34)LHD(35)LHD(36)LHD(37)LHD(38)LHD(39)LHD(40)LHD(41)LHD(42)LHD(43)LHD(44)LHD(45)
#undef LHD
  }

  unsigned long long mask_prev = 0ull;
  float ndv = (wid == 0) ? negd[l] : 0.f;

  for (int n = 0; n < NBLK; ++n) {
    int t0 = n * 64;
    if (wid == 0) {
      int tn = t0 + 64 + l;
      float ndnext = (tn < T_DATA) ? negd[tn] : INFINITY;
      int par = n & 1;
      float X = deepb[par][0][l] + deepb[par][1][l] + deepb[par][2][l];
      // boundary conv: prev-block bit i adds hb(63-i) — pure register math
      {
        float a0 = 0.f, a1 = 0.f, a2 = 0.f, a3 = 0.f;
#define BD(i, hv, acc) acc = fmaf((float)((mask_prev >> (i)) & 1ull), hv, acc);
        BD(0,hb63,a0)BD(1,hb62,a1)BD(2,hb61,a2)BD(3,hb60,a3)
        BD(4,hb59,a0)BD(5,hb58,a1)BD(6,hb57,a2)BD(7,hb56,a3)
        BD(8,hb55,a0)BD(9,hb54,a1)BD(10,hb53,a2)BD(11,hb52,a3)
        BD(12,hb51,a0)BD(13,hb50,a1)BD(14,hb49,a2)BD(15,hb48,a3)
        BD(16,hb47,a0)BD(17,hb46,a1)BD(18,hb45,a2)BD(19,hb44,a3)
        BD(20,hb43,a0)BD(21,hb42,a1)BD(22,hb41,a2)BD(23,hb40,a3)
        BD(24,hb39,a0)BD(25,hb38,a1)BD(26,hb37,a2)BD(27,hb36,a3)
        BD(28,hb35,a0)BD(29,hb34,a1)BD(30,hb33,a2)BD(31,hb32,a3)
        BD(32,hb31,a0)BD(33,hb30,a1)BD(34,hb29,a2)BD(35,hb28,a3)
        BD(36,hb27,a0)BD(37,hb26,a1)BD(38,hb25,a2)BD(39,hb24,a3)
        BD(40,hb23,a0)BD(41,hb22,a1)BD(42,hb21,a2)BD(43,hb20,a3)
        BD(44,hb19,a0)BD(45,hb18,a1)BD(46,hb17,a2)BD(47,hb16,a3)
        BD(48,hb15,a0)BD(49,hb14,a1)BD(50,hb13,a2)BD(51,hb12,a3)
        BD(52,hb11,a0)BD(53,hb10,a1)BD(54,hb9,a2)BD(55,hb8,a3)
        BD(56,hb7,a0)BD(57,hb6,a1)BD(58,hb5,a2)BD(59,hb4,a3)
        BD(60,hb3,a0)BD(61,hb2,a1)BD(62,hb1,a2)BD(63,hb0,a3)
#undef BD
        X += (a0 + a1) + (a2 + a3);
      }
      // spike-sparse left-to-right finalization
      unsigned long long msk;
      int pos = -1;
      while (1) {
        unsigned long long bm = __ballot(X > ndv);
        unsigned long long below = (pos < 0) ? 0ull : ((1ull << (pos + 1)) - 1ull);
        unsigned long long rem = bm & ~below;
        if (rem == 0ull) { msk = bm; break; }     // bits<=pos stable, rest 0
        int q = (int)__builtin_ctzll(rem);        // next definite spike (uniform)
        int c = l - q - 1;                        // hist index for lane l
        float hv = __shfl(H, c & 63, 64);         // hist[c] from lane c
        if (c >= 0) X += hv;
        if (q >= 63) { msk = bm; break; }         // no lanes after 63
        pos = q;
      }
      // publish: spike output + block mask
      float myspk = (float)((msk >> l) & 1ull);
      int t = t0 + l;
      if (t < T_DATA) out_spk[t] = myspk;
      if (l == 0) mring[n & 7] = msk;
      mask_prev = msk;
      ndv = ndnext;
    } else {
      // deep feedback for block n+1 from spike bitmasks of blocks n-1..n-3.
      unsigned long long M1 = mring[(n + 7) & 7];
      unsigned long long M2 = mring[(n + 6) & 7];
      unsigned long long M3 = mring[(n + 5) & 7];
      M1 = ((unsigned long long)__builtin_amdgcn_readfirstlane((unsigned)(M1 >> 32)) << 32)
           | (unsigned)__builtin_amdgcn_readfirstlane((unsigned)M1);
      M2 = ((unsigned long long)__builtin_amdgcn_readfirstlane((unsigned)(M2 >> 32)) << 32)
           | (unsigned)__builtin_amdgcn_readfirstlane((unsigned)M2);
      M3 = ((unsigned long long)__builtin_amdgcn_readfirstlane((unsigned)(M3 >> 32)) << 32)
           | (unsigned)__builtin_amdgcn_readfirstlane((unsigned)M3);
      float a0 = 0.f, a1 = 0.f, a2 = 0.f, a3 = 0.f;
#define DT(j, M, b, acc) acc = fmaf((float)(((M) >> (b)) & 1ull), hd##j, acc);
      if (wid == 1) {
        DT(0,M1,63,a0)DT(1,M1,62,a1)DT(2,M1,61,a2)DT(3,M1,60,a3)
        DT(4,M1,59,a0)DT(5,M1,58,a1)DT(6,M1,57,a2)DT(7,M1,56,a3)
        DT(8,M1,55,a0)DT(9,M1,54,a1)DT(10,M1,53,a2)DT(11,M1,52,a3)
        DT(12,M1,51,a0)DT(13,M1,50,a1)DT(14,M1,49,a2)DT(15,M1,48,a3)
        DT(16,M1,47,a0)DT(17,M1,46,a1)DT(18,M1,45,a2)DT(19,M1,44,a3)
        DT(20,M1,43,a0)DT(21,M1,42,a1)DT(22,M1,41,a2)DT(23,M1,40,a3)
        DT(24,M1,39,a0)DT(25,M1,38,a1)DT(26,M1,37,a2)DT(27,M1,36,a3)
        DT(28,M1,35,a0)DT(29,M1,34,a1)DT(30,M1,33,a2)DT(31,M1,32,a3)
        DT(32,M1,31,a0)DT(33,M1,30,a1)DT(34,M1,29,a2)DT(35,M1,28,a3)
        DT(36,M1,27,a0)DT(37,M1,26,a1)DT(38,M1,25,a2)DT(39,M1,24,a3)
        DT(40,M1,23,a0)DT(41,M1,22,a1)DT(42,M1,21,a2)DT(43,M1,20,a3)
        DT(44,M1,19,a0)DT(45,M1,18,a1)
      } else if (wid == 2) {
        DT(0,M1,17,a0)DT(1,M1,16,a1)DT(2,M1,15,a2)DT(3,M1,14,a3)
        DT(4,M1,13,a0)DT(5,M1,12,a1)DT(6,M1,11,a2)DT(7,M1,10,a3)
        DT(8,M1,9,a0)DT(9,M1,8,a1)DT(10,M1,7,a2)DT(11,M1,6,a3)
        DT(12,M1,5,a0)DT(13,M1,4,a1)DT(14,M1,3,a2)DT(15,M1,2,a3)
        DT(16,M1,1,a0)DT(17,M1,0,a1)
        DT(18,M2,63,a2)DT(19,M2,62,a3)
        DT(20,M2,61,a0)DT(21,M2,60,a1)DT(22,M2,59,a2)DT(23,M2,58,a3)
        DT(24,M2,57,a0)DT(25,M2,56,a1)DT(26,M2,55,a2)DT(27,M2,54,a3)
        DT(28,M2,53,a0)DT(29,M2,52,a1)DT(30,M2,51,a2)DT(31,M2,50,a3)
        DT(32,M2,49,a0)DT(33,M2,48,a1)DT(34,M2,47,a2)DT(35,M2,46,a3)
        DT(36,M2,45,a0)DT(37,M2,44,a1)DT(38,M2,43,a2)DT(39,M2,42,a3)
        DT(40,M2,41,a0)DT(41,M2,40,a1)DT(42,M2,39,a2)DT(43,M2,38,a3)
        DT(44,M2,37,a0)
      } else {
        DT(0,M2,36,a0)DT(1,M2,35,a1)DT(2,M2,34,a2)DT(3,M2,33,a3)
        DT(4,M2,32,a0)DT(5,M2,31,a1)DT(6,M2,30,a2)DT(7,M2,29,a3)
        DT(8,M2,28,a0)DT(9,M2,27,a1)DT(10,M2,26,a2)DT(11,M2,25,a3)
        DT(12,M2,24,a0)DT(13,M2,23,a1)DT(14,M2,22,a2)DT(15,M2,21,a3)
        DT(16,M2,20,a0)DT(17,M2,19,a1)DT(18,M2,18,a2)DT(19,M2,17,a3)
        DT(20,M2,16,a0)DT(21,M2,15,a1)DT(22,M2,14,a2)DT(23,M2,13,a3)
        DT(24,M2,12,a0)DT(25,M2,11,a1)DT(26,M2,10,a2)DT(27,M2,9,a3)
        DT(28,M2,8,a0)DT(29,M2,7,a1)DT(30,M2,6,a2)DT(31,M2,5,a3)
        DT(32,M2,4,a0)DT(33,M2,3,a1)DT(34,M2,2,a2)DT(35,M2,1,a3)
        DT(36,M2,0,a0)
        DT(37,M3,63,a1)DT(38,M3,62,a2)DT(39,M3,61,a3)
        DT(40,M3,60,a0)DT(41,M3,59,a1)DT(42,M3,58,a2)DT(43,M3,57,a3)
        DT(44,M3,56,a0)
      }
#undef DT
      deepb[(n + 1) & 1][wid - 1][l] = (a0 + a1) + (a2 + a3);
    }
    __syncthreads();
  }
}

// ---------------------------------------------------------------------------
extern "C" void kernel_launch(void* const* d_in, const int* in_sizes, int n_in,
                              void* d_out, int out_size, void* d_ws, size_t ws_size,
                              hipStream_t stream) {
  const float* S_e      = (const float*)d_in[0];
  const float* S_i      = (const float*)d_in[1];
  const int*   C_den    = (const int*)d_in[2];
  const float* C_syn_e  = (const float*)d_in[3];
  const float* C_syn_i  = (const float*)d_in[4];
  const float* cos_b    = (const float*)d_in[5];
  const float* Tau_e    = (const float*)d_in[6];
  const float* Tau_i    = (const float*)d_in[7];
  const float* W_e      = (const float*)d_in[8];
  const float* W_i      = (const float*)d_in[9];
  const float* D_e      = (const float*)d_in[10];
  const float* D_i      = (const float*)d_in[11];
  const float* W_sub    = (const float*)d_in[12];
  const float* W_hist   = (const float*)d_in[13];
  const float* Theta    = (const float*)d_in[14];
  float* out = (float*)d_out;

  float* wsf      = (float*)d_ws;
  float* ws_ek    = wsf;
  float* ws_ik    = wsf + 3200;
  float* ws_hist  = wsf + 6400;
  float* ws_ewsub = wsf + 6600;
  float* ws_we    = wsf + 6616;
  float* ws_wi    = wsf + 8616;
  float* synE     = wsf + 16384;
  float* synI     = wsf + 336384;
  float* negd     = wsf + 656384;
  int*   ws_me    = (int*)(wsf + 676384);
  int*   ws_mi    = (int*)(wsf + 678384);
  int*   ws_cmask = (int*)(wsf + 678884);

  k_prep<<<dim3(1), dim3(256), 0, stream>>>(
      C_syn_e, C_syn_i, cos_b, Tau_e, Tau_i, W_e, W_i, D_e, D_i, W_sub, W_hist,
      C_den, ws_ek, ws_ik, ws_hist, ws_ewsub, ws_we, ws_wi, ws_me, ws_mi,
      ws_cmask, out + T_DATA);

  k_agg<<<dim3(1250), dim3(256), 0, stream>>>(
      (const float4*)S_e, (const float4*)S_i, ws_me, ws_we, ws_mi, ws_wi,
      synE, synI);

  k_filt<<<dim3(NBLK), dim3(64), 0, stream>>>(
      synE, synI, ws_ek, ws_ik, Theta, ws_ewsub, ws_cmask, negd);

  k_scan<<<dim3(1), dim3(256), 0, stream>>>(ws_hist, negd, out);
}

// Round 8
// 786.626 us; speedup vs baseline: 3.2077x; 3.2077x over previous
//
#include <hip/hip_runtime.h>
#include <math.h>
#include <stdint.h>

#define T_DATA 20000
#define E_NO   2000
#define I_NO   500
#define SUB    16
#define TNO    200
#define NBLK   313   // ceil(20000/64)

// ---------------- workspace layout (float offsets) ----------------
// 0       ek[3200]   (s*200+t)
// 3200    ik[3200]
// 6400    hist[200]
// 6600    ewsub[16]
// 6616    we[2000]
// 8616    wi[500]
// 16384   synE[20000*16]
// 336384  synI[20000*16]
// 656384  negd[20000]
// 676384  me[2000] (int)
// 678384  mi[500]  (int)
// 678884  cmask[16](int)

// ---------------------------------------------------------------------------
// K1: per-subunit kernels, hist kernel, synapse->subunit maps, tree masks.
// ---------------------------------------------------------------------------
__global__ __launch_bounds__(256) void k_prep(
    const float* __restrict__ Ce, const float* __restrict__ Ci,
    const float* __restrict__ cosb,
    const float* __restrict__ TauE, const float* __restrict__ TauI,
    const float* __restrict__ We,  const float* __restrict__ Wi,
    const float* __restrict__ De,  const float* __restrict__ Di,
    const float* __restrict__ Wsub, const float* __restrict__ Whist,
    const int* __restrict__ Cden,
    float* __restrict__ ws_ek, float* __restrict__ ws_ik,
    float* __restrict__ ws_hist, float* __restrict__ ws_ewsub,
    float* __restrict__ ws_we, float* __restrict__ ws_wi,
    int* __restrict__ ws_me, int* __restrict__ ws_mi, int* __restrict__ ws_cmask,
    float* __restrict__ out_filt) {
  int tid = threadIdx.x;
  for (int idx = tid; idx < SUB * TNO; idx += 256) {
    int s = idx / TNO;
    float tf = (float)(idx % TNO);
    float te  = fmaxf(tf - expf(De[s]), 0.f);
    float tte = te / expf(TauE[s]);
    float ekv = tte * expf(-tte) * expf(We[s]);
    float ti_ = fmaxf(tf - expf(Di[s]), 0.f);
    float tti = ti_ / expf(TauI[s]);
    float ikv = -(tti * expf(-tti) * expf(Wi[s]));
    ws_ek[idx] = ekv;
    ws_ik[idx] = ikv;
    out_filt[idx] = ekv;            // rows 0..15
    out_filt[3200 + idx] = ikv;     // rows 16..31
  }
  for (int t = tid; t < TNO; t += 256) {
    float h = 0.f;
    for (int b = 0; b < 16; ++b) h = fmaf(Whist[b], cosb[b * TNO + t], h);
    ws_hist[t] = h;
    out_filt[6400 + t] = h;         // row 32 (unflipped)
  }
  for (int e = tid; e < E_NO; e += 256) {
    int m = 0; float w = 0.f;
    for (int s = 0; s < SUB; ++s) {
      float v = Ce[s * E_NO + e];
      if (w == 0.f && v != 0.f) { m = s; w = v; }
    }
    ws_me[e] = m; ws_we[e] = w;
  }
  for (int e = tid; e < I_NO; e += 256) {
    int m = 0; float w = 0.f;
    for (int s = 0; s < SUB; ++s) {
      float v = Ci[s * I_NO + e];
      if (w == 0.f && v != 0.f) { m = s; w = v; }
    }
    ws_mi[e] = m; ws_wi[e] = w;
  }
  if (tid < SUB) {
    ws_ewsub[tid] = expf(Wsub[tid]);
    int msk = 0;
    for (int j = 0; j < SUB; ++j)
      if (Cden[tid * SUB + j] == 1) msk |= (1 << j);
    ws_cmask[tid] = msk;
  }
}

// ---------------------------------------------------------------------------
// K2: synapse aggregation -> synE/synI [20000][16]. Deterministic.
// ---------------------------------------------------------------------------
__global__ __launch_bounds__(256) void k_agg(
    const float4* __restrict__ Se4, const float4* __restrict__ Si4,
    const int* __restrict__ me, const float* __restrict__ we,
    const int* __restrict__ mi, const float* __restrict__ wi,
    float* __restrict__ synE, float* __restrict__ synI) {
  __shared__ float bins[4][64][33];
  int tid = threadIdx.x, wid = tid >> 6, l = tid & 63;
  int gw = blockIdx.x * 4 + wid;
  for (int r = 0; r < 4; ++r) {
    int t = gw * 4 + r;
#pragma unroll
    for (int s = 0; s < 32; ++s) bins[wid][l][s] = 0.f;
    for (int i = 0; i < 8; ++i) {
      int idx = i * 64 + l;
      if (idx < 500) {
        float4 v = Se4[(size_t)t * 500 + idx];
        int e0 = idx * 4;
        if (v.x != 0.f) bins[wid][l][me[e0 + 0]] += v.x * we[e0 + 0];
        if (v.y != 0.f) bins[wid][l][me[e0 + 1]] += v.y * we[e0 + 1];
        if (v.z != 0.f) bins[wid][l][me[e0 + 2]] += v.z * we[e0 + 2];
        if (v.w != 0.f) bins[wid][l][me[e0 + 3]] += v.w * we[e0 + 3];
      }
    }
    for (int i = 0; i < 2; ++i) {
      int idx = i * 64 + l;
      if (idx < 125) {
        float4 v = Si4[(size_t)t * 125 + idx];
        int e0 = idx * 4;
        if (v.x != 0.f) bins[wid][l][16 + mi[e0 + 0]] += v.x * wi[e0 + 0];
        if (v.y != 0.f) bins[wid][l][16 + mi[e0 + 1]] += v.y * wi[e0 + 1];
        if (v.z != 0.f) bins[wid][l][16 + mi[e0 + 2]] += v.z * wi[e0 + 2];
        if (v.w != 0.f) bins[wid][l][16 + mi[e0 + 3]] += v.w * wi[e0 + 3];
      }
    }
    __syncthreads();
    if (l < 32) {
      float a = 0.f;
      for (int k = 0; k < 64; ++k) a += bins[wid][k][l];
      if (l < 16) synE[(size_t)t * 16 + l] = a;
      else        synI[(size_t)t * 16 + (l - 16)] = a;
    }
    __syncthreads();
  }
}

// ---------------------------------------------------------------------------
// K3: causal filtering + dendritic tree -> negd[t] = -drive[t].
// ---------------------------------------------------------------------------
__global__ __launch_bounds__(64) void k_filt(
    const float* __restrict__ synE, const float* __restrict__ synI,
    const float* __restrict__ ek_ws, const float* __restrict__ ik_ws,
    const float* __restrict__ theta, const float* __restrict__ ewsub,
    const int* __restrict__ cmask,
    float* __restrict__ negd) {
  __shared__ float sE[264 * 17];
  __shared__ float sI[264 * 17];
  __shared__ float ekl[TNO * 16];
  __shared__ float ikl[TNO * 16];
  int l = threadIdx.x;
  int t0 = blockIdx.x * 64;
  for (int idx = l; idx < 264 * 16; idx += 64) {
    int row = idx >> 4, s = idx & 15;
    int g = t0 - 200 + row;
    bool ok = (g >= 0) && (g < T_DATA);
    sE[row * 17 + s] = ok ? synE[(size_t)g * 16 + s] : 0.f;
    sI[row * 17 + s] = ok ? synI[(size_t)g * 16 + s] : 0.f;
  }
  for (int idx = l; idx < SUB * TNO; idx += 64) {
    int s = idx / TNO, j = idx % TNO;
    ekl[j * 16 + s] = ek_ws[idx];
    ikl[j * 16 + s] = ik_ws[idx];
  }
  __syncthreads();
  int t = t0 + l;
  float acc[16];
#pragma unroll
  for (int s = 0; s < 16; ++s) acc[s] = 0.f;
  for (int j = 0; j < TNO; ++j) {
    int base = (l + 199 - j) * 17;
    int kb = j * 16;
#pragma unroll
    for (int s = 0; s < 16; ++s)
      acc[s] = fmaf(ekl[kb + s], sE[base + s], fmaf(ikl[kb + s], sI[base + s], acc[s]));
  }
  float th[16], ew[16]; int cm[16];
#pragma unroll
  for (int s = 0; s < 16; ++s) { th[s] = theta[s]; ew[s] = ewsub[s]; cm[s] = cmask[s]; }
  float val[16];
#pragma unroll
  for (int s = 0; s < 16; ++s) val[s] = 0.f;
#pragma unroll
  for (int sidx = 15; sidx >= 1; --sidx) {
    float sum = acc[sidx] + th[sidx];
#pragma unroll
    for (int j = 0; j < 16; ++j)
      if ((cm[sidx] >> j) & 1) sum += val[j] * ew[j];
    val[sidx] = tanhf(sum);
  }
  float drive = acc[0] + th[0];
#pragma unroll
  for (int j = 0; j < 16; ++j)
    if ((cm[0] >> j) & 1) drive += val[j] * ew[j];
  if (t < T_DATA) negd[t] = -drive;
}

// ---------------------------------------------------------------------------
// K4: sequential spike scan. 1 workgroup, 4 waves (one per SIMD).
// ROUND 8: spike density ~50% (R7 evidence) -> fixed 64-step chain, but with
// per-step latency cut two ways:
//  (a) raw `v_cmp_gt_f32 sgpr_pair, v, v` inline asm = single-instruction
//      ballot (HIP __ballot costs 3 dependent VALU ops);
//  (b) 2-step lookahead: per pair (i,i+1), ballot bm0 on X and bm1 on X+hA
//      (speculative: spike-at-i applied). Bit i of bm0 is final (s0); bit
//      i+1 = bit of (s0 ? bm1 : bm0) via s_cselect. One chain segment
//      resolves TWO steps: ~45cyc/pair vs ~80cyc/step before.
// Wave0 holds h0..h127 in named regs (chain taps h(63-i), boundary taps
// h(127-i)); deep waves keep R6's mask+register form (measured cheap).
// ---------------------------------------------------------------------------
__global__
__attribute__((amdgpu_flat_work_group_size(256, 256), amdgpu_waves_per_eu(1, 1)))
void k_scan(
    const float* __restrict__ hist, const float* __restrict__ negd,
    float* __restrict__ out_spk) {
  __shared__ float hpad[328];        // [0..63]=0, [64..263]=h[0..199], [264..327]=0
  __shared__ unsigned long long mring[8];  // per-block spike masks, slot n&7
  __shared__ float deepb[2][3][64];  // parity double-buffered deep partials
  int tid = threadIdx.x, wid = tid >> 6, l = tid & 63;
  for (int i = tid; i < 328; i += 256) hpad[i] = (i >= 64 && i < 264) ? hist[i - 64] : 0.f;
  if (tid < 8) mring[tid] = 0ull;
  for (int i = tid; i < 2 * 3 * 64; i += 256) (&deepb[0][0][0])[i] = 0.f;
  __syncthreads();

  // wave0: h(j) = hpad[l + j].  chain step i adds h(63-i); boundary tap i
  // adds h(127-i).
  float h0=0,h1=0,h2=0,h3=0,h4=0,h5=0,h6=0,h7=0,h8=0,h9=0,h10=0,h11=0,h12=0,h13=0,h14=0,h15=0,
        h16=0,h17=0,h18=0,h19=0,h20=0,h21=0,h22=0,h23=0,h24=0,h25=0,h26=0,h27=0,h28=0,h29=0,h30=0,h31=0,
        h32=0,h33=0,h34=0,h35=0,h36=0,h37=0,h38=0,h39=0,h40=0,h41=0,h42=0,h43=0,h44=0,h45=0,h46=0,h47=0,
        h48=0,h49=0,h50=0,h51=0,h52=0,h53=0,h54=0,h55=0,h56=0,h57=0,h58=0,h59=0,h60=0,h61=0,h62=0,h63=0,
        h64=0,h65=0,h66=0,h67=0,h68=0,h69=0,h70=0,h71=0,h72=0,h73=0,h74=0,h75=0,h76=0,h77=0,h78=0,h79=0,
        h80=0,h81=0,h82=0,h83=0,h84=0,h85=0,h86=0,h87=0,h88=0,h89=0,h90=0,h91=0,h92=0,h93=0,h94=0,h95=0,
        h96=0,h97=0,h98=0,h99=0,h100=0,h101=0,h102=0,h103=0,h104=0,h105=0,h106=0,h107=0,h108=0,h109=0,h110=0,h111=0,
        h112=0,h113=0,h114=0,h115=0,h116=0,h117=0,h118=0,h119=0,h120=0,h121=0,h122=0,h123=0,h124=0,h125=0,h126=0,h127=0;
  // deep-wave tap registers: hd(j) = hpad[dbase + l + j]
  float hd0=0,hd1=0,hd2=0,hd3=0,hd4=0,hd5=0,hd6=0,hd7=0,hd8=0,hd9=0,hd10=0,hd11=0,hd12=0,hd13=0,hd14=0,hd15=0,
        hd16=0,hd17=0,hd18=0,hd19=0,hd20=0,hd21=0,hd22=0,hd23=0,hd24=0,hd25=0,hd26=0,hd27=0,hd28=0,hd29=0,hd30=0,hd31=0,
        hd32=0,hd33=0,hd34=0,hd35=0,hd36=0,hd37=0,hd38=0,hd39=0,hd40=0,hd41=0,hd42=0,hd43=0,hd44=0,hd45=0;
  if (wid == 0) {
#define LD(j) h##j = hpad[l + j];
    LD(0)LD(1)LD(2)LD(3)LD(4)LD(5)LD(6)LD(7)LD(8)LD(9)LD(10)LD(11)LD(12)LD(13)LD(14)LD(15)
    LD(16)LD(17)LD(18)LD(19)LD(20)LD(21)LD(22)LD(23)LD(24)LD(25)LD(26)LD(27)LD(28)LD(29)LD(30)LD(31)
    LD(32)LD(33)LD(34)LD(35)LD(36)LD(37)LD(38)LD(39)LD(40)LD(41)LD(42)LD(43)LD(44)LD(45)LD(46)LD(47)
    LD(48)LD(49)LD(50)LD(51)LD(52)LD(53)LD(54)LD(55)LD(56)LD(57)LD(58)LD(59)LD(60)LD(61)LD(62)LD(63)
    LD(64)LD(65)LD(66)LD(67)LD(68)LD(69)LD(70)LD(71)LD(72)LD(73)LD(74)LD(75)LD(76)LD(77)LD(78)LD(79)
    LD(80)LD(81)LD(82)LD(83)LD(84)LD(85)LD(86)LD(87)LD(88)LD(89)LD(90)LD(91)LD(92)LD(93)LD(94)LD(95)
    LD(96)LD(97)LD(98)LD(99)LD(100)LD(101)LD(102)LD(103)LD(104)LD(105)LD(106)LD(107)LD(108)LD(109)LD(110)LD(111)
    LD(112)LD(113)LD(114)LD(115)LD(116)LD(117)LD(118)LD(119)LD(120)LD(121)LD(122)LD(123)LD(124)LD(125)LD(126)LD(127)
#undef LD
  } else {
    int dbase = (wid == 2) ? 174 : (wid == 3) ? 219 : 128;
#define LHD(j) hd##j = hpad[dbase + l + j];
    LHD(0)LHD(1)LHD(2)LHD(3)LHD(4)LHD(5)LHD(6)LHD(7)LHD(8)LHD(9)LHD(10)LHD(11)LHD(12)LHD(13)LHD(14)LHD(15)
    LHD(16)LHD(17)LHD(18)LHD(19)LHD(20)LHD(21)LHD(22)LHD(23)LHD(24)LHD(25)LHD(26)LHD(27)LHD(28)LHD(29)LHD(30)LHD(31)
    LHD(32)LHD(33)LHD(34)LHD(35)LHD(36)LHD(37)LHD(38)LHD(39)LHD(40)LHD(41)LHD(42)LHD(43)LHD(44)LHD(45)
#undef LHD
  }

  unsigned long long mask_prev = 0ull;
  float ndv = (wid == 0) ? negd[l] : 0.f;

  for (int n = 0; n < NBLK; ++n) {
    int t0 = n * 64;
    if (wid == 0) {
      int tn = t0 + 64 + l;
      float ndnext = (tn < T_DATA) ? negd[tn] : INFINITY;
      int par = n & 1;
      float X = deepb[par][0][l] + deepb[par][1][l] + deepb[par][2][l];
      // boundary conv: prev-block bit i adds h(127-i) — pure register math
      {
        float a0 = 0.f, a1 = 0.f, a2 = 0.f, a3 = 0.f;
#define BD(i, hv, acc) acc = fmaf((float)((mask_prev >> (i)) & 1ull), hv, acc);
        BD(0,h127,a0)BD(1,h126,a1)BD(2,h125,a2)BD(3,h124,a3)
        BD(4,h123,a0)BD(5,h122,a1)BD(6,h121,a2)BD(7,h120,a3)
        BD(8,h119,a0)BD(9,h118,a1)BD(10,h117,a2)BD(11,h116,a3)
        BD(12,h115,a0)BD(13,h114,a1)BD(14,h113,a2)BD(15,h112,a3)
        BD(16,h111,a0)BD(17,h110,a1)BD(18,h109,a2)BD(19,h108,a3)
        BD(20,h107,a0)BD(21,h106,a1)BD(22,h105,a2)BD(23,h104,a3)
        BD(24,h103,a0)BD(25,h102,a1)BD(26,h101,a2)BD(27,h100,a3)
        BD(28,h99,a0)BD(29,h98,a1)BD(30,h97,a2)BD(31,h96,a3)
        BD(32,h95,a0)BD(33,h94,a1)BD(34,h93,a2)BD(35,h92,a3)
        BD(36,h91,a0)BD(37,h90,a1)BD(38,h89,a2)BD(39,h88,a3)
        BD(40,h87,a0)BD(41,h86,a1)BD(42,h85,a2)BD(43,h84,a3)
        BD(44,h83,a0)BD(45,h82,a1)BD(46,h81,a2)BD(47,h80,a3)
        BD(48,h79,a0)BD(49,h78,a1)BD(50,h77,a2)BD(51,h76,a3)
        BD(52,h75,a0)BD(53,h74,a1)BD(54,h73,a2)BD(55,h72,a3)
        BD(56,h71,a0)BD(57,h70,a1)BD(58,h69,a2)BD(59,h68,a3)
        BD(60,h67,a0)BD(61,h66,a1)BD(62,h65,a2)BD(63,h64,a3)
#undef BD
        X += (a0 + a1) + (a2 + a3);
      }
      // 2-step lookahead chain: 32 pairs cover steps 0..63
      unsigned long long msk = 0ull;
#define CH2(i, hvA, hvB) { \
      float Xa = X + hvA; \
      unsigned long long bm0, bm1; \
      asm("v_cmp_gt_f32 %0, %2, %4\n\t" \
          "v_cmp_gt_f32 %1, %3, %4" \
          : "=s"(bm0), "=s"(bm1) : "v"(X), "v"(Xa), "v"(ndv)); \
      unsigned s0b = (unsigned)(bm0 >> (i)) & 1u; \
      unsigned long long bmx = s0b ? bm1 : bm0; \
      unsigned s1b = (unsigned)(bmx >> ((i) + 1)) & 1u; \
      float s0f = (float)s0b, s1f = (float)s1b; \
      X = fmaf(s0f, hvA, X); \
      X = fmaf(s1f, hvB, X); \
      msk |= ((unsigned long long)s0b << (i)) | ((unsigned long long)s1b << ((i) + 1)); }
      CH2(0,h63,h62)  CH2(2,h61,h60)  CH2(4,h59,h58)  CH2(6,h57,h56)
      CH2(8,h55,h54)  CH2(10,h53,h52) CH2(12,h51,h50) CH2(14,h49,h48)
      CH2(16,h47,h46) CH2(18,h45,h44) CH2(20,h43,h42) CH2(22,h41,h40)
      CH2(24,h39,h38) CH2(26,h37,h36) CH2(28,h35,h34) CH2(30,h33,h32)
      CH2(32,h31,h30) CH2(34,h29,h28) CH2(36,h27,h26) CH2(38,h25,h24)
      CH2(40,h23,h22) CH2(42,h21,h20) CH2(44,h19,h18) CH2(46,h17,h16)
      CH2(48,h15,h14) CH2(50,h13,h12) CH2(52,h11,h10) CH2(54,h9,h8)
      CH2(56,h7,h6)   CH2(58,h5,h4)   CH2(60,h3,h2)   CH2(62,h1,h0)
#undef CH2
      // publish: spike output + block mask
      float myspk = (float)((msk >> l) & 1ull);
      int t = t0 + l;
      if (t < T_DATA) out_spk[t] = myspk;
      if (l == 0) mring[n & 7] = msk;
      mask_prev = msk;
      ndv = ndnext;
    } else {
      // deep feedback for block n+1 from spike bitmasks of blocks n-1..n-3.
      unsigned long long M1 = mring[(n + 7) & 7];
      unsigned long long M2 = mring[(n + 6) & 7];
      unsigned long long M3 = mring[(n + 5) & 7];
      M1 = ((unsigned long long)__builtin_amdgcn_readfirstlane((unsigned)(M1 >> 32)) << 32)
           | (unsigned)__builtin_amdgcn_readfirstlane((unsigned)M1);
      M2 = ((unsigned long long)__builtin_amdgcn_readfirstlane((unsigned)(M2 >> 32)) << 32)
           | (unsigned)__builtin_amdgcn_readfirstlane((unsigned)M2);
      M3 = ((unsigned long long)__builtin_amdgcn_readfirstlane((unsigned)(M3 >> 32)) << 32)
           | (unsigned)__builtin_amdgcn_readfirstlane((unsigned)M3);
      float a0 = 0.f, a1 = 0.f, a2 = 0.f, a3 = 0.f;
#define DT(j, M, b, acc) acc = fmaf((float)(((M) >> (b)) & 1ull), hd##j, acc);
      if (wid == 1) {
        DT(0,M1,63,a0)DT(1,M1,62,a1)DT(2,M1,61,a2)DT(3,M1,60,a3)
        DT(4,M1,59,a0)DT(5,M1,58,a1)DT(6,M1,57,a2)DT(7,M1,56,a3)
        DT(8,M1,55,a0)DT(9,M1,54,a1)DT(10,M1,53,a2)DT(11,M1,52,a3)
        DT(12,M1,51,a0)DT(13,M1,50,a1)DT(14,M1,49,a2)DT(15,M1,48,a3)
        DT(16,M1,47,a0)DT(17,M1,46,a1)DT(18,M1,45,a2)DT(19,M1,44,a3)
        DT(20,M1,43,a0)DT(21,M1,42,a1)DT(22,M1,41,a2)DT(23,M1,40,a3)
        DT(24,M1,39,a0)DT(25,M1,38,a1)DT(26,M1,37,a2)DT(27,M1,36,a3)
        DT(28,M1,35,a0)DT(29,M1,34,a1)DT(30,M1,33,a2)DT(31,M1,32,a3)
        DT(32,M1,31,a0)DT(33,M1,30,a1)DT(34,M1,29,a2)DT(35,M1,28,a3)
        DT(36,M1,27,a0)DT(37,M1,26,a1)DT(38,M1,25,a2)DT(39,M1,24,a3)
        DT(40,M1,23,a0)DT(41,M1,22,a1)DT(42,M1,21,a2)DT(43,M1,20,a3)
        DT(44,M1,19,a0)DT(45,M1,18,a1)
      } else if (wid == 2) {
        DT(0,M1,17,a0)DT(1,M1,16,a1)DT(2,M1,15,a2)DT(3,M1,14,a3)
        DT(4,M1,13,a0)DT(5,M1,12,a1)DT(6,M1,11,a2)DT(7,M1,10,a3)
        DT(8,M1,9,a0)DT(9,M1,8,a1)DT(10,M1,7,a2)DT(11,M1,6,a3)
        DT(12,M1,5,a0)DT(13,M1,4,a1)DT(14,M1,3,a2)DT(15,M1,2,a3)
        DT(16,M1,1,a0)DT(17,M1,0,a1)
        DT(18,M2,63,a2)DT(19,M2,62,a3)
        DT(20,M2,61,a0)DT(21,M2,60,a1)DT(22,M2,59,a2)DT(23,M2,58,a3)
        DT(24,M2,57,a0)DT(25,M2,56,a1)DT(26,M2,55,a2)DT(27,M2,54,a3)
        DT(28,M2,53,a0)DT(29,M2,52,a1)DT(30,M2,51,a2)DT(31,M2,50,a3)
        DT(32,M2,49,a0)DT(33,M2,48,a1)DT(34,M2,47,a2)DT(35,M2,46,a3)
        DT(36,M2,45,a0)DT(37,M2,44,a1)DT(38,M2,43,a2)DT(39,M2,42,a3)
        DT(40,M2,41,a0)DT(41,M2,40,a1)DT(42,M2,39,a2)DT(43,M2,38,a3)
        DT(44,M2,37,a0)
      } else {
        DT(0,M2,36,a0)DT(1,M2,35,a1)DT(2,M2,34,a2)DT(3,M2,33,a3)
        DT(4,M2,32,a0)DT(5,M2,31,a1)DT(6,M2,30,a2)DT(7,M2,29,a3)
        DT(8,M2,28,a0)DT(9,M2,27,a1)DT(10,M2,26,a2)DT(11,M2,25,a3)
        DT(12,M2,24,a0)DT(13,M2,23,a1)DT(14,M2,22,a2)DT(15,M2,21,a3)
        DT(16,M2,20,a0)DT(17,M2,19,a1)DT(18,M2,18,a2)DT(19,M2,17,a3)
        DT(20,M2,16,a0)DT(21,M2,15,a1)DT(22,M2,14,a2)DT(23,M2,13,a3)
        DT(24,M2,12,a0)DT(25,M2,11,a1)DT(26,M2,10,a2)DT(27,M2,9,a3)
        DT(28,M2,8,a0)DT(29,M2,7,a1)DT(30,M2,6,a2)DT(31,M2,5,a3)
        DT(32,M2,4,a0)DT(33,M2,3,a1)DT(34,M2,2,a2)DT(35,M2,1,a3)
        DT(36,M2,0,a0)
        DT(37,M3,63,a1)DT(38,M3,62,a2)DT(39,M3,61,a3)
        DT(40,M3,60,a0)DT(41,M3,59,a1)DT(42,M3,58,a2)DT(43,M3,57,a3)
        DT(44,M3,56,a0)
      }
#undef DT
      deepb[(n + 1) & 1][wid - 1][l] = (a0 + a1) + (a2 + a3);
    }
    __syncthreads();
  }
}

// ---------------------------------------------------------------------------
extern "C" void kernel_launch(void* const* d_in, const int* in_sizes, int n_in,
                              void* d_out, int out_size, void* d_ws, size_t ws_size,
                              hipStream_t stream) {
  const float* S_e      = (const float*)d_in[0];
  const float* S_i      = (const float*)d_in[1];
  const int*   C_den    = (const int*)d_in[2];
  const float* C_syn_e  = (const float*)d_in[3];
  const float* C_syn_i  = (const float*)d_in[4];
  const float* cos_b    = (const float*)d_in[5];
  const float* Tau_e    = (const float*)d_in[6];
  const float* Tau_i    = (const float*)d_in[7];
  const float* W_e      = (const float*)d_in[8];
  const float* W_i      = (const float*)d_in[9];
  const float* D_e      = (const float*)d_in[10];
  const float* D_i      = (const float*)d_in[11];
  const float* W_sub    = (const float*)d_in[12];
  const float* W_hist   = (const float*)d_in[13];
  const float* Theta    = (const float*)d_in[14];
  float* out = (float*)d_out;

  float* wsf      = (float*)d_ws;
  float* ws_ek    = wsf;
  float* ws_ik    = wsf + 3200;
  float* ws_hist  = wsf + 6400;
  float* ws_ewsub = wsf + 6600;
  float* ws_we    = wsf + 6616;
  float* ws_wi    = wsf + 8616;
  float* synE     = wsf + 16384;
  float* synI     = wsf + 336384;
  float* negd     = wsf + 656384;
  int*   ws_me    = (int*)(wsf + 676384);
  int*   ws_mi    = (int*)(wsf + 678384);
  int*   ws_cmask = (int*)(wsf + 678884);

  k_prep<<<dim3(1), dim3(256), 0, stream>>>(
      C_syn_e, C_syn_i, cos_b, Tau_e, Tau_i, W_e, W_i, D_e, D_i, W_sub, W_hist,
      C_den, ws_ek, ws_ik, ws_hist, ws_ewsub, ws_we, ws_wi, ws_me, ws_mi,
      ws_cmask, out + T_DATA);

  k_agg<<<dim3(1250), dim3(256), 0, stream>>>(
      (const float4*)S_e, (const float4*)S_i, ws_me, ws_we, ws_mi, ws_wi,
      synE, synI);

  k_filt<<<dim3(NBLK), dim3(64), 0, stream>>>(
      synE, synI, ws_ek, ws_ik, Theta, ws_ewsub, ws_cmask, negd);

  k_scan<<<dim3(1), dim3(256), 0, stream>>>(ws_hist, negd, out);
}